// Round 3
// baseline (408.819 us; speedup 1.0000x reference)
//
#include <hip/hip_runtime.h>
#include <math.h>

// Problem constants (fixed by setup_inputs: B=16,K=32,L=1024,D=128,NEW_L=48)
constexpr int CB = 16, CK = 32, CL = 1024, CD = 128, CNL = 48;

// Output offsets (in floats), concatenated in return order:
// new_h0 (B,K,NL,D), new_event_time (B,K,NL), new_pad_mask (B,K,NL), almat (B,K,L,NL)
constexpr size_t OUT_H0 = 0;
constexpr size_t OUT_ET = (size_t)CB * CNL * CK * CD;              // 3,145,728
constexpr size_t OUT_PM = OUT_ET + (size_t)CB * CK * CNL;          // +24,576
constexpr size_t OUT_AL = OUT_PM + (size_t)CB * CK * CNL;          // +24,576

// Monotone map float -> u32 so that unsigned max == float max.
__device__ __forceinline__ unsigned fmap(float f) {
    int i = __float_as_int(f);
    return (i >= 0) ? ((unsigned)i | 0x80000000u) : ~(unsigned)i;
}
__device__ __forceinline__ float funmap(unsigned u) {
    return (u & 0x80000000u) ? __int_as_float((int)(u & 0x7FFFFFFFu))
                             : __int_as_float(~(int)u);
}
// fmap(-INFINITY) == 0x007FFFFF
#define FMAP_NEG_INF 0x007FFFFFu

// ---------------------------------------------------------------------------
// Kernel 1: per-batch seg index + counts + tsum histograms.
// ---------------------------------------------------------------------------
__global__ __launch_bounds__(256) void seg_kernel(
    const float* __restrict__ et, int* __restrict__ seg,
    float* __restrict__ counts, float* __restrict__ tsum) {
    __shared__ float cnt_s[CNL];
    __shared__ float ts_s[CNL];
    const int b = blockIdx.x;
    const int t = threadIdx.x;
    if (t < CNL) { cnt_s[t] = 0.f; ts_s[t] = 0.f; }
    __syncthreads();
    for (int l = t; l < CL; l += 256) {
        float e = et[b * CL + l];
        bool valid = (e >= 0.f) && (e < (float)CNL);
        int s = valid ? (int)floorf(e) : CNL;
        seg[b * CL + l] = s;
        if (valid) {
            atomicAdd(&cnt_s[s], 1.f);
            atomicAdd(&ts_s[s], e);
        }
    }
    __syncthreads();
    if (t < CNL) {
        counts[b * CNL + t] = cnt_s[t];
        tsum[b * CNL + t] = ts_s[t];
    }
}

// ---------------------------------------------------------------------------
// Kernel 2: per-(b,k) segment-max of h0 rows + msum; writes new_h0,
// new_event_time, new_pad_mask.
// Block = 512 threads = 4 row-groups x 128 lanes (lane owns column d).
// Accumulator: (CNL+1) x 128 u32 (mapped floats) in LDS, updated with
// LDS atomicMax (slot CNL is a dump for invalid segs; never read back).
// ---------------------------------------------------------------------------
__global__ __launch_bounds__(512) void main_kernel(
    const float* __restrict__ h0, const float* __restrict__ npm,
    const int* __restrict__ seg, const float* __restrict__ counts,
    const float* __restrict__ tsum, float* __restrict__ out) {
    __shared__ unsigned acc[(CNL + 1) * CD];   // 25,088 B
    __shared__ float msum_s[CNL + 1];
    __shared__ int segl[CL];                   // 4 KB

    const int bk = blockIdx.x;
    const int b = bk >> 5;
    const int t = threadIdx.x;

    for (int c = t; c < (CNL + 1) * CD; c += 512) acc[c] = FMAP_NEG_INF;
    if (t < CNL + 1) msum_s[t] = 0.f;
    for (int l = t; l < CL; l += 512) segl[l] = seg[b * CL + l];
    __syncthreads();

    // ---- msum: sum npm[b,k,l] per segment (float2 per thread) ----
    {
        const float2* nrow = (const float2*)(npm + (size_t)bk * CL);
        float2 v = nrow[t];
        int l2 = t * 2;
        atomicAdd(&msum_s[segl[l2 + 0]], v.x);
        atomicAdd(&msum_s[segl[l2 + 1]], v.y);
    }

    // ---- segment-max over rows ----
    const float* hbase = h0 + (size_t)bk * CL * CD;
    const int rg = t >> 7;       // row group 0..3
    const int d = t & 127;       // column
    const int base = rg * 256;   // each group owns 256 consecutive rows
    for (int i = 0; i < 256; i += 4) {
        const int l0 = base + i;
        float v0 = hbase[(size_t)(l0 + 0) * CD + d];
        float v1 = hbase[(size_t)(l0 + 1) * CD + d];
        float v2 = hbase[(size_t)(l0 + 2) * CD + d];
        float v3 = hbase[(size_t)(l0 + 3) * CD + d];
        int s0 = segl[l0 + 0];
        int s1 = segl[l0 + 1];
        int s2 = segl[l0 + 2];
        int s3 = segl[l0 + 3];
        atomicMax(&acc[s0 * CD + d], fmap(v0));
        atomicMax(&acc[s1 * CD + d], fmap(v1));
        atomicMax(&acc[s2 * CD + d], fmap(v2));
        atomicMax(&acc[s3 * CD + d], fmap(v3));
    }
    __syncthreads();

    // ---- epilogue: new_h0 with clamp-if-counts<L ----
    // Reference layout after transpose(0,2,1,3): (b, k, new_l, d)
    for (int c = t; c < CNL * CD; c += 512) {
        int s = c >> 7;
        float v = funmap(acc[c]);
        float cn = counts[b * CNL + s];
        if (cn < (float)CL) v = fmaxf(v, 0.f);
        out[OUT_H0 + (size_t)bk * CNL * CD + c] = v;
    }
    if (t < CNL) {
        float cn = counts[b * CNL + t];
        float den = fmaxf(cn, 1.f);
        out[OUT_ET + (size_t)bk * CNL + t] = tsum[b * CNL + t] / den;
        out[OUT_PM + (size_t)bk * CNL + t] = msum_s[t] / den;
    }
}

// ---------------------------------------------------------------------------
// Kernel 3: almat one-hot, float4 coalesced writes.
// ---------------------------------------------------------------------------
__global__ __launch_bounds__(256) void almat_kernel(
    const int* __restrict__ seg, float4* __restrict__ out) {
    const int total4 = CB * CK * CL * (CNL / 4);   // 6,291,456
    const int stride = gridDim.x * blockDim.x;
    for (int i = blockIdx.x * blockDim.x + threadIdx.x; i < total4; i += stride) {
        int row = i / 12;            // (b*K + k)*L + l
        int c4 = i - row * 12;
        int l = row & (CL - 1);
        int b = row >> 15;           // row / (K*L)
        int s = seg[(b << 10) + l];
        int c = c4 * 4;
        float4 v;
        v.x = (c + 0 == s) ? 1.f : 0.f;
        v.y = (c + 1 == s) ? 1.f : 0.f;
        v.z = (c + 2 == s) ? 1.f : 0.f;
        v.w = (c + 3 == s) ? 1.f : 0.f;
        out[i] = v;
    }
}

// ---------------------------------------------------------------------------
extern "C" void kernel_launch(void* const* d_in, const int* in_sizes, int n_in,
                              void* d_out, int out_size, void* d_ws, size_t ws_size,
                              hipStream_t stream) {
    (void)in_sizes; (void)n_in; (void)out_size; (void)ws_size;
    const float* h0  = (const float*)d_in[0];
    const float* et  = (const float*)d_in[1];
    const float* npm = (const float*)d_in[2];
    // d_in[3] = new_l (48, hardcoded)
    float* out = (float*)d_out;

    // ws layout: seg int[B*L] (64 KB) | counts float[B*NL] | tsum float[B*NL]
    int* seg = (int*)d_ws;
    float* counts = (float*)((char*)d_ws + (size_t)CB * CL * sizeof(int));
    float* tsum = counts + CB * CNL;

    seg_kernel<<<CB, 256, 0, stream>>>(et, seg, counts, tsum);
    main_kernel<<<CB * CK, 512, 0, stream>>>(h0, npm, seg, counts, tsum, out);
    almat_kernel<<<4096, 256, 0, stream>>>(seg, (float4*)(out + OUT_AL));
}